// Round 2
// baseline (155.372 us; speedup 1.0000x reference)
//
#include <hip/hip_runtime.h>
#include <math.h>

// Problem constants: B=2, N=256, C=5, H=4, DH=8, HID=32, FF=20
#define NN 256
#define CC 5
#define HIDD 32

// Round-2: single-kernel pipeline. Measured time is ~92% harness poison
// fills (3 x 39.5us on the 256MiB workspace, uncontrollable); the owned
// budget is ~10.4us. Changes vs R1:
//  - head MLP fused via last-block ticket (fence + atomicAdd); counter base
//    derived from an untouched poison word 16B away (uniform fill pattern),
//    counter reset by the last block for graph replay correctness.
//  - PWL table build driven by per-bin knot-activity bitmasks; iterate set
//    bits ascending -> identical FP op sequence, ~0 work for empty bins
//    (with rb1==0 all middle bins are empty). (R1,rb1),(R2k,R2v) packed as
//    float2 -> b64 LDS reads.
//  - 2-hop adjacency loads issued 8-deep before the table build (no barrier
//    between) so L2 latency hides under it; knot sort/masks moved into the
//    q0/ykr phase using wave-0 in-order LDS semantics.
//  - epilogue entirely in wave 0 (in-wave LDS ordering): 4 barriers removed,
//    waves 1-3 retire early.
// FP op order identical to the 129us version (absmax 0.0 expected).

__device__ __forceinline__ float gelu_tanh(float x) {
    float x3 = x * x * x;
    return 0.5f * x * (1.0f + tanhf(0.7978845608028654f * (x + 0.044715f * x3)));
}
__device__ __forceinline__ float sgnf(float x) {
    return (x > 0.f) ? 1.f : ((x < 0.f) ? -1.f : 0.f);
}

#define TROW 9           // table row = 9 float4 = 36 floats (32 used + pad)
#define TSZ (33 * TROW)  // one table, in float4 units

__global__ __launch_bounds__(256) void fused_all(
    const float* __restrict__ coors,
    const int* __restrict__ adj,
    const float* __restrict__ feats,
    const float* __restrict__ Wq0, const float* __restrict__ Mk0, const float* __restrict__ Mv0,
    const float* __restrict__ gnA0, const float* __restrict__ bnA0,
    const float* __restrict__ R1, const float* __restrict__ rb1,
    const float* __restrict__ R2, const float* __restrict__ rb2,
    const float* __restrict__ Wo0,  // (32,5)
    const float* __restrict__ gnF0, const float* __restrict__ bnF0,
    const float* __restrict__ Wf10, // (C,20)
    const float* __restrict__ Wf20, // (20,C)
    const float* __restrict__ Wh1, const float* __restrict__ bh1,
    const float* __restrict__ Wh2, const float* __restrict__ bh2,
    float* __restrict__ xfin,       // (512,5)
    int* __restrict__ ctr, const int* __restrict__ refw,
    float* __restrict__ out)        // (2,9)
{
    int node = blockIdx.x;
    int b = node >> 8, i = node & 255;
    int tid = threadIdx.x;
    int j = tid;
    int lane = tid & 63, wave = tid >> 6;

    __shared__ float4 sT[4 * TSZ];          // A|B|C|D tables
    __shared__ float2 kv[32][32];           // (R2[w][hd], R2[w][192+hd])
    __shared__ float2 srr[32];              // (R1[w], rb1[w])
    __shared__ float srb2k[32], srb2v[32];
    __shared__ float tt[32], sts[32];
    __shared__ unsigned int smask[33];      // per-bin knot-activity mask
    __shared__ float q0s[32];
    __shared__ float Wo0t[5][32];
    __shared__ int nlist[NN];
    __shared__ int ncnt;
    __shared__ float wredm[4][4], wreds[4][4], hm[4], hs[4];
    __shared__ float ew[4][5], x0as[5], xfs[5], h0s[20];
    __shared__ float part[2][5][25], pooled[10], hdn[2][128];

    // ---- R0: stage weights, own adjacency entry, dist, own-node LN ----
    int av = adj[(size_t)(b * NN + i) * NN + j];   // adj[i][j]

    for (int idx = tid; idx < 1024; idx += 256) {
        int w = idx >> 5, hd = idx & 31;
        kv[w][hd] = make_float2(R2[w * 384 + hd], R2[w * 384 + 192 + hd]);
    }
    if (tid < 32) {
        srr[tid] = make_float2(R1[tid], rb1[tid]);
        srb2k[tid] = rb2[tid];
        srb2v[tid] = rb2[192 + tid];
    }
    if (tid < 160) Wo0t[tid / 32][tid % 32] = Wo0[(tid % 32) * 5 + tid / 32];
    if (tid == 0) ncnt = 0;

    // dist(i,j)
    float dx = coors[(b * NN + j) * 3 + 0] - coors[(b * NN + i) * 3 + 0];
    float dy = coors[(b * NN + j) * 3 + 1] - coors[(b * NN + i) * 3 + 1];
    float dz = coors[(b * NN + j) * 3 + 2] - coors[(b * NN + i) * 3 + 2];
    float dist = sqrtf(dx * dx + dy * dy + dz * dz + 1e-12f);

    // own node-j normalized scalar features x0n
    float x0n[CC];
    {
        const float* f = feats + (size_t)(b * NN + j) * CC;
        float fv[CC], n0[CC];
        float mu = 0.f;
#pragma unroll
        for (int c = 0; c < CC; c++) { fv[c] = f[c]; n0[c] = fabsf(fv[c]); mu += n0[c]; }
        mu *= (1.0f / CC);
        float var = 0.f;
#pragma unroll
        for (int c = 0; c < CC; c++) { float d = n0[c] - mu; var += d * d; }
        var *= (1.0f / CC);
        float sd = sqrtf(var) + 1e-8f;
#pragma unroll
        for (int c = 0; c < CC; c++) {
            float ln = (n0[c] - mu) / sd * gnA0[c] + bnA0[c];
            x0n[c] = sgnf(fv[c]) * gelu_tanh(ln);
        }
    }
    __syncthreads();   // B1: srr/kv staged, ncnt=0 published

    // ---- A: knots+sort+masks+q0 (wave 0, in-order LDS) | nlist | ykr ----
    if (tid < 32) {
        float r = srr[tid].x;
        tt[tid] = (r != 0.f) ? (-srr[tid].y / r) : -3.0e38f;
    }
    if (tid < 32) {   // sort (reads tt written by same wave -> ordered)
        float t = tt[tid];
        int rank = 0;
        for (int k = 0; k < 32; k++) {
            float tk = tt[k];
            rank += (tk < t) || (tk == t && k < tid);
        }
        sts[rank] = t;
    }
    if (tid < 33) {   // per-bin activity mask (lane 32 still wave 0)
        float rep = (tid == 0) ? (sts[0] - 1.0f)
                  : (tid == 32) ? (sts[31] + 1.0f)
                  : 0.5f * (sts[tid - 1] + sts[tid]);
        unsigned int m = 0;
        for (int w = 0; w < 32; w++) {
            float2 rr = srr[w];
            if (fmaf(rr.x, rep, rr.y) > 0.f) m |= (1u << w);
        }
        smask[tid] = m;
    }
    if (tid < 32) {   // q0[i][tid]
        const float* f = feats + (size_t)(b * NN + i) * CC;
        float fv[CC], n0[CC], xi[CC];
        float mu = 0.f;
#pragma unroll
        for (int c = 0; c < CC; c++) { fv[c] = f[c]; n0[c] = fabsf(fv[c]); mu += n0[c]; }
        mu *= (1.0f / CC);
        float var = 0.f;
#pragma unroll
        for (int c = 0; c < CC; c++) { float d = n0[c] - mu; var += d * d; }
        var *= (1.0f / CC);
        float sd = sqrtf(var) + 1e-8f;
#pragma unroll
        for (int c = 0; c < CC; c++) {
            float ln = (n0[c] - mu) / sd * gnA0[c] + bnA0[c];
            xi[c] = sgnf(fv[c]) * gelu_tanh(ln);
        }
        float q = 0.f;
#pragma unroll
        for (int c = 0; c < CC; c++) q = fmaf(xi[c], Wq0[c * HIDD + tid], q);
        q0s[tid] = q;
    }
    if (av) { int p = atomicAdd(&ncnt, 1); nlist[p] = j; }

    // yk[j][0..31] in registers
    float ykr[32];
#pragma unroll
    for (int hd = 0; hd < 32; hd++) ykr[hd] = 0.f;
#pragma unroll
    for (int c = 0; c < CC; c++) {
        float xc = x0n[c];
#pragma unroll
        for (int hd = 0; hd < 32; hd++)
            ykr[hd] = fmaf(xc, Mk0[c * HIDD + hd], ykr[hd]);
    }
    __syncthreads();   // B2: sts/smask/q0s/nlist ready

    // ---- B: 2-hop loads (8-deep, issued first) + mask-driven table build ----
    int okacc = (av != 0) || (i == j);
    {
        int cnt = ncnt;
        for (int t = 0; t < cnt; t += 8) {
            int idxs[8], vv[8];
#pragma unroll
            for (int k = 0; k < 8; k++) {
                int u = t + k;
                idxs[k] = nlist[(u < cnt) ? u : t];   // dup tail: OR-idempotent
            }
#pragma unroll
            for (int k = 0; k < 8; k++)
                vv[k] = adj[(size_t)(b * NN + idxs[k]) * NN + j];  // coalesced over j
#pragma unroll
            for (int k = 0; k < 8; k++) okacc |= vv[k];
        }
    }
    for (int idx = tid; idx < 33 * 32; idx += 256) {
        int p = idx >> 5, hd = idx & 31;
        unsigned int m = smask[p];
        float A = 0.f, Bv = 0.f, Cv = 0.f, Dv = 0.f;
        while (m) {                       // ascending w == reference order
            int w = __ffs(m) - 1;
            m &= (m - 1);
            float2 rr = srr[w];
            float2 kw = kv[w][hd];
            A  = fmaf(rr.x, kw.x, A);  Bv = fmaf(rr.y, kw.x, Bv);
            Cv = fmaf(rr.x, kw.y, Cv); Dv = fmaf(rr.y, kw.y, Dv);
        }
        Bv += srb2k[hd];
        Dv += srb2v[hd];
        float* tf = (float*)sT;
        tf[(0 * TSZ + p * TROW) * 4 + hd] = A;
        tf[(1 * TSZ + p * TROW) * 4 + hd] = Bv;
        tf[(2 * TSZ + p * TROW) * 4 + hd] = Cv;
        tf[(3 * TSZ + p * TROW) * 4 + hd] = Dv;
    }
    __syncthreads();   // B3: table ready

    // ---- logits via PWL table ----
    int p = 0;
#pragma unroll
    for (int k = 0; k < 32; k++) p += (sts[k] < dist) ? 1 : 0;

    const float4* Ap = sT + 0 * TSZ + p * TROW;
    const float4* Bp = sT + 1 * TSZ + p * TROW;
    const float4* Cp = sT + 2 * TSZ + p * TROW;
    const float4* Dp = sT + 3 * TSZ + p * TROW;
    const float4* q04 = (const float4*)q0s;

    float lg[4] = {0.f, 0.f, 0.f, 0.f};
#pragma unroll
    for (int q = 0; q < 8; q++) {
        float4 a = Ap[q], bb = Bp[q], qq = q04[q];
        int h = q >> 1;
        lg[h] = fmaf(fmaf(dist, a.x, bb.x) * qq.x, ykr[4 * q + 0], lg[h]);
        lg[h] = fmaf(fmaf(dist, a.y, bb.y) * qq.y, ykr[4 * q + 1], lg[h]);
        lg[h] = fmaf(fmaf(dist, a.z, bb.z) * qq.z, ykr[4 * q + 2], lg[h]);
        lg[h] = fmaf(fmaf(dist, a.w, bb.w) * qq.w, ykr[4 * q + 3], lg[h]);
    }
    {
        const float invs = 0.35355339059327379f; // 1/sqrt(8)
        bool ok = okacc != 0;
#pragma unroll
        for (int h = 0; h < 4; h++) lg[h] = ok ? lg[h] * invs : -1e9f;
    }

    // block softmax over j, per head
    float attn[4];
#pragma unroll
    for (int h = 0; h < 4; h++) {
        float v = lg[h];
        for (int off = 32; off; off >>= 1) v = fmaxf(v, __shfl_xor(v, off, 64));
        if (lane == 0) wredm[h][wave] = v;
    }
    __syncthreads();
    if (tid < 4) hm[tid] = fmaxf(fmaxf(wredm[tid][0], wredm[tid][1]), fmaxf(wredm[tid][2], wredm[tid][3]));
    __syncthreads();
#pragma unroll
    for (int h = 0; h < 4; h++) lg[h] = expf(lg[h] - hm[h]);
#pragma unroll
    for (int h = 0; h < 4; h++) {
        float v = lg[h];
        for (int off = 32; off; off >>= 1) v += __shfl_xor(v, off, 64);
        if (lane == 0) wreds[h][wave] = v;
    }
    __syncthreads();
    if (tid < 4) hs[tid] = wreds[tid][0] + wreds[tid][1] + wreds[tid][2] + wreds[tid][3];
    __syncthreads();
#pragma unroll
    for (int h = 0; h < 4; h++) attn[h] = lg[h] / hs[h];

    // yv[j][0..31] projected after softmax (VGPR peak)
    float yvr[32];
#pragma unroll
    for (int hd = 0; hd < 32; hd++) yvr[hd] = 0.f;
#pragma unroll
    for (int c = 0; c < CC; c++) {
        float xc = x0n[c];
#pragma unroll
        for (int hd = 0; hd < 32; hd++)
            yvr[hd] = fmaf(xc, Mv0[c * HIDD + hd], yvr[hd]);
    }

    // v-phase with Wo0 folded
    float e[5] = {0.f, 0.f, 0.f, 0.f, 0.f};
#pragma unroll
    for (int q = 0; q < 8; q++) {
        float4 c4 = Cp[q], d4 = Dp[q];
        float at = attn[q >> 1];
        float4 pv;
        pv.x = at * fmaf(dist, c4.x, d4.x) * yvr[4 * q + 0];
        pv.y = at * fmaf(dist, c4.y, d4.y) * yvr[4 * q + 1];
        pv.z = at * fmaf(dist, c4.z, d4.z) * yvr[4 * q + 2];
        pv.w = at * fmaf(dist, c4.w, d4.w) * yvr[4 * q + 3];
#pragma unroll
        for (int c = 0; c < 5; c++) {
            float4 w4 = ((const float4*)Wo0t[c])[q];
            e[c] = fmaf(pv.x, w4.x, fmaf(pv.y, w4.y, fmaf(pv.z, w4.z, fmaf(pv.w, w4.w, e[c]))));
        }
    }
    for (int off = 32; off; off >>= 1)
#pragma unroll
        for (int c = 0; c < 5; c++) e[c] += __shfl_xor(e[c], off, 64);
    if (lane == 0)
#pragma unroll
        for (int c = 0; c < 5; c++) ew[wave][c] = e[c];
    __syncthreads();   // last block-wide barrier; waves 1-3 exit after this

    if (wave != 0) return;

    // ---- epilogue entirely in wave 0 (in-wave LDS ordering, no barriers) ----
    if (lane < 5) {
        float d0 = ew[0][lane] + ew[1][lane] + ew[2][lane] + ew[3][lane];
        x0as[lane] = feats[node * 5 + lane] + d0;
    }
    if (lane < 5) {
        float x0a[5], n0[5];
        float mu = 0.f;
#pragma unroll
        for (int c = 0; c < 5; c++) { x0a[c] = x0as[c]; n0[c] = fabsf(x0a[c]); mu += n0[c]; }
        mu *= 0.2f;
        float var = 0.f;
#pragma unroll
        for (int c = 0; c < 5; c++) { float d = n0[c] - mu; var += d * d; }
        var *= 0.2f;
        float sd = sqrtf(var) + 1e-8f;
        float ln = (n0[lane] - mu) / sd * gnF0[lane] + bnF0[lane];
        xfs[lane] = sgnf(x0a[lane]) * gelu_tanh(ln);
    }
    if (lane < 20) {
        float s = 0.f;
#pragma unroll
        for (int c = 0; c < 5; c++) s = fmaf(xfs[c], Wf10[c * 20 + lane], s);
        h0s[lane] = gelu_tanh(s);
    }
    if (lane < 5) {
        float f0 = 0.f;
        for (int f = 0; f < 20; f++) f0 = fmaf(h0s[f], Wf20[f * 5 + lane], f0);
        xfin[node * 5 + lane] = x0as[lane] + f0;
    }

    // ---- last-block ticket: run the head MLP once all xfin are written ----
    __threadfence();                       // release our xfin stores (device scope)
    int slast = 0, base = 0;
    if (lane == 0) {
        base = __hip_atomic_load(refw, __ATOMIC_RELAXED, __HIP_MEMORY_SCOPE_AGENT);
        int old = __hip_atomic_fetch_add(ctr, 1, __ATOMIC_ACQ_REL, __HIP_MEMORY_SCOPE_AGENT);
        slast = ((old - base) == 511) ? 1 : 0;
    }
    slast = __shfl(slast, 0, 64);
    if (!slast) return;

    __threadfence();                       // acquire side, belt-and-suspenders

    // head MLP, 64 lanes, FP op order identical to the old head_mlp kernel
    for (int tpl = lane; tpl < 250; tpl += 64) {
        int bb = tpl / 125, r = tpl % 125, c = r / 25, grp = r % 25;
        float s = 0.f;
        for (int ii = grp; ii < NN; ii += 25) s += xfin[(bb * NN + ii) * 5 + c];
        part[bb][c][grp] = s;
    }
    if (lane < 10) {
        int bb = lane / 5, c = lane % 5;
        float s = 0.f;
        for (int g = 0; g < 25; g++) s += part[bb][c][g];
        pooled[lane] = s * (1.0f / NN);
    }
    for (int kk = lane; kk < 256; kk += 64) {
        int bb = kk >> 7, k = kk & 127;
        float s = bh1[k];
#pragma unroll
        for (int c = 0; c < 5; c++) s = fmaf(pooled[bb * 5 + c], Wh1[c * 128 + k], s);
        hdn[bb][k] = fmaxf(s, 0.f);
    }
    if (lane < 18) {
        int bb = lane / 9, o = lane % 9;
        float s = bh2[o];
        for (int k = 0; k < 128; k++) s = fmaf(hdn[bb][k], Wh2[k * 9 + o], s);
        out[bb * 9 + o] = s;
    }
    if (lane == 0) {
        // restore counter so the next graph replay starts from the poison base
        __hip_atomic_store(ctr, base, __ATOMIC_RELAXED, __HIP_MEMORY_SCOPE_AGENT);
    }
}

extern "C" void kernel_launch(void* const* d_in, const int* in_sizes, int n_in,
                              void* d_out, int out_size, void* d_ws, size_t ws_size,
                              hipStream_t stream) {
    const float* feats = (const float*)d_in[0];
    const float* coors = (const float*)d_in[1];
    const int*   adj   = (const int*)d_in[2];
    const float* Wq    = (const float*)d_in[3];
    const float* Mk    = (const float*)d_in[4];
    const float* Mv    = (const float*)d_in[5];
    const float* R1    = (const float*)d_in[6];
    const float* rb1   = (const float*)d_in[7];
    const float* R2    = (const float*)d_in[8];
    const float* rb2   = (const float*)d_in[9];
    const float* Wo0   = (const float*)d_in[10];
    const float* gnA   = (const float*)d_in[12];
    const float* bnA   = (const float*)d_in[13];
    const float* gnF   = (const float*)d_in[14];
    const float* bnF   = (const float*)d_in[15];
    const float* Wf1   = (const float*)d_in[16];
    const float* Wf2   = (const float*)d_in[17];
    const float* Wh1   = (const float*)d_in[20];
    const float* bh1   = (const float*)d_in[21];
    const float* Wh2   = (const float*)d_in[22];
    const float* bh2   = (const float*)d_in[23];
    float* out = (float*)d_out;

    // workspace: xfin at 0 (512*5 floats = 10240B); ticket counter at +16384,
    // poison-reference word at +16400 (same fill value for any pattern period
    // dividing 16B). The ref word is never written by the kernel.
    float* xfin = (float*)d_ws;
    int* ctr    = (int*)((char*)d_ws + 16384);
    const int* refw = (const int*)((char*)d_ws + 16400);

    hipLaunchKernelGGL(fused_all, dim3(512), dim3(256), 0, stream,
                       coors, adj, feats, Wq, Mk, Mv, gnA, bnA, R1, rb1, R2, rb2,
                       Wo0, gnF, bnF, Wf1, Wf2, Wh1, bh1, Wh2, bh2,
                       xfin, ctr, refw, out);
}

// Round 3
// 125.325 us; speedup vs baseline: 1.2398x; 1.2398x over previous
//
#include <hip/hip_runtime.h>
#include <math.h>

// Problem constants: B=2, N=256, C=5, H=4, DH=8, HID=32, FF=20
#define NN 256
#define CC 5
#define HIDD 32

// Round-3: REVERT the single-kernel ticket (R2 post-mortem: agent-scope
// __threadfence + atomic on CDNA4 = L2 writeback across 8 non-coherent XCD
// L2s; 512 blocks x that = ~54us stall, vs ~2us for a launch boundary).
// Back to 2 kernels, keeping R2's orthogonal wins:
//  - bitmask-driven PWL table build (identical FP order, ~0 work empty bins)
//  - float2-packed (R1,rb1) and (R2k,R2v) LDS staging (b64 reads)
//  - 8-deep prefetched 2-hop adjacency loads overlapped with table build
//  - wave-0-only epilogue (in-wave LDS ordering, no barriers)
// New in R3: softmax cross-wave reduction without the tid<4 stage -> each
// thread reduces the 4 per-wave partials itself (same FP order), removing
// 2 __syncthreads. 6 barriers total.

__device__ __forceinline__ float gelu_tanh(float x) {
    float x3 = x * x * x;
    return 0.5f * x * (1.0f + tanhf(0.7978845608028654f * (x + 0.044715f * x3)));
}
__device__ __forceinline__ float sgnf(float x) {
    return (x > 0.f) ? 1.f : ((x < 0.f) ? -1.f : 0.f);
}

#define TROW 9           // table row = 9 float4 = 36 floats (32 used + pad)
#define TSZ (33 * TROW)  // one table, in float4 units

__global__ __launch_bounds__(256) void fused_attn(
    const float* __restrict__ coors,
    const int* __restrict__ adj,
    const float* __restrict__ feats,
    const float* __restrict__ Wq0, const float* __restrict__ Mk0, const float* __restrict__ Mv0,
    const float* __restrict__ gnA0, const float* __restrict__ bnA0,
    const float* __restrict__ R1, const float* __restrict__ rb1,
    const float* __restrict__ R2, const float* __restrict__ rb2,
    const float* __restrict__ Wo0,  // (32,5)
    const float* __restrict__ gnF0, const float* __restrict__ bnF0,
    const float* __restrict__ Wf10, // (C,20)
    const float* __restrict__ Wf20, // (20,C)
    float* __restrict__ xfin)       // (512,5)
{
    int node = blockIdx.x;
    int b = node >> 8, i = node & 255;
    int tid = threadIdx.x;
    int j = tid;
    int lane = tid & 63, wave = tid >> 6;

    __shared__ float4 sT[4 * TSZ];          // A|B|C|D tables
    __shared__ float2 kv[32][32];           // (R2[w][hd], R2[w][192+hd])
    __shared__ float2 srr[32];              // (R1[w], rb1[w])
    __shared__ float srb2k[32], srb2v[32];
    __shared__ float tt[32], sts[32];
    __shared__ unsigned int smask[33];      // per-bin knot-activity mask
    __shared__ float q0s[32];
    __shared__ float Wo0t[5][32];
    __shared__ int nlist[NN];
    __shared__ int ncnt;
    __shared__ float wredm[4][4], wreds[4][4];
    __shared__ float ew[4][5], x0as[5], xfs[5], h0s[20];

    // ---- R0: stage weights, own adjacency entry, dist, own-node LN ----
    int av = adj[(size_t)(b * NN + i) * NN + j];   // adj[i][j]

    for (int idx = tid; idx < 1024; idx += 256) {
        int w = idx >> 5, hd = idx & 31;
        kv[w][hd] = make_float2(R2[w * 384 + hd], R2[w * 384 + 192 + hd]);
    }
    if (tid < 32) {
        srr[tid] = make_float2(R1[tid], rb1[tid]);
        srb2k[tid] = rb2[tid];
        srb2v[tid] = rb2[192 + tid];
    }
    if (tid < 160) Wo0t[tid / 32][tid % 32] = Wo0[(tid % 32) * 5 + tid / 32];
    if (tid == 0) ncnt = 0;

    // dist(i,j)
    float dx = coors[(b * NN + j) * 3 + 0] - coors[(b * NN + i) * 3 + 0];
    float dy = coors[(b * NN + j) * 3 + 1] - coors[(b * NN + i) * 3 + 1];
    float dz = coors[(b * NN + j) * 3 + 2] - coors[(b * NN + i) * 3 + 2];
    float dist = sqrtf(dx * dx + dy * dy + dz * dz + 1e-12f);

    // own node-j normalized scalar features x0n
    float x0n[CC];
    {
        const float* f = feats + (size_t)(b * NN + j) * CC;
        float fv[CC], n0[CC];
        float mu = 0.f;
#pragma unroll
        for (int c = 0; c < CC; c++) { fv[c] = f[c]; n0[c] = fabsf(fv[c]); mu += n0[c]; }
        mu *= (1.0f / CC);
        float var = 0.f;
#pragma unroll
        for (int c = 0; c < CC; c++) { float d = n0[c] - mu; var += d * d; }
        var *= (1.0f / CC);
        float sd = sqrtf(var) + 1e-8f;
#pragma unroll
        for (int c = 0; c < CC; c++) {
            float ln = (n0[c] - mu) / sd * gnA0[c] + bnA0[c];
            x0n[c] = sgnf(fv[c]) * gelu_tanh(ln);
        }
    }
    __syncthreads();   // B1: srr/kv staged, ncnt=0 published

    // ---- A: knots+sort+masks+q0 (wave 0, in-order LDS) | nlist | ykr ----
    if (tid < 32) {
        float r = srr[tid].x;
        tt[tid] = (r != 0.f) ? (-srr[tid].y / r) : -3.0e38f;
    }
    if (tid < 32) {   // sort (reads tt written by same wave -> ordered)
        float t = tt[tid];
        int rank = 0;
        for (int k = 0; k < 32; k++) {
            float tk = tt[k];
            rank += (tk < t) || (tk == t && k < tid);
        }
        sts[rank] = t;
    }
    if (tid < 33) {   // per-bin activity mask (lane 32 still wave 0)
        float rep = (tid == 0) ? (sts[0] - 1.0f)
                  : (tid == 32) ? (sts[31] + 1.0f)
                  : 0.5f * (sts[tid - 1] + sts[tid]);
        unsigned int m = 0;
        for (int w = 0; w < 32; w++) {
            float2 rr = srr[w];
            if (fmaf(rr.x, rep, rr.y) > 0.f) m |= (1u << w);
        }
        smask[tid] = m;
    }
    if (tid < 32) {   // q0[i][tid]
        const float* f = feats + (size_t)(b * NN + i) * CC;
        float fv[CC], n0[CC], xi[CC];
        float mu = 0.f;
#pragma unroll
        for (int c = 0; c < CC; c++) { fv[c] = f[c]; n0[c] = fabsf(fv[c]); mu += n0[c]; }
        mu *= (1.0f / CC);
        float var = 0.f;
#pragma unroll
        for (int c = 0; c < CC; c++) { float d = n0[c] - mu; var += d * d; }
        var *= (1.0f / CC);
        float sd = sqrtf(var) + 1e-8f;
#pragma unroll
        for (int c = 0; c < CC; c++) {
            float ln = (n0[c] - mu) / sd * gnA0[c] + bnA0[c];
            xi[c] = sgnf(fv[c]) * gelu_tanh(ln);
        }
        float q = 0.f;
#pragma unroll
        for (int c = 0; c < CC; c++) q = fmaf(xi[c], Wq0[c * HIDD + tid], q);
        q0s[tid] = q;
    }
    if (av) { int p = atomicAdd(&ncnt, 1); nlist[p] = j; }

    // yk[j][0..31] in registers
    float ykr[32];
#pragma unroll
    for (int hd = 0; hd < 32; hd++) ykr[hd] = 0.f;
#pragma unroll
    for (int c = 0; c < CC; c++) {
        float xc = x0n[c];
#pragma unroll
        for (int hd = 0; hd < 32; hd++)
            ykr[hd] = fmaf(xc, Mk0[c * HIDD + hd], ykr[hd]);
    }
    __syncthreads();   // B2: sts/smask/q0s/nlist ready

    // ---- B: 2-hop loads (8-deep, issued first) + mask-driven table build ----
    int okacc = (av != 0) || (i == j);
    {
        int cnt = ncnt;
        for (int t = 0; t < cnt; t += 8) {
            int idxs[8], vv[8];
#pragma unroll
            for (int k = 0; k < 8; k++) {
                int u = t + k;
                idxs[k] = nlist[(u < cnt) ? u : t];   // dup tail: OR-idempotent
            }
#pragma unroll
            for (int k = 0; k < 8; k++)
                vv[k] = adj[(size_t)(b * NN + idxs[k]) * NN + j];  // coalesced over j
#pragma unroll
            for (int k = 0; k < 8; k++) okacc |= vv[k];
        }
    }
    for (int idx = tid; idx < 33 * 32; idx += 256) {
        int p = idx >> 5, hd = idx & 31;
        unsigned int m = smask[p];
        float A = 0.f, Bv = 0.f, Cv = 0.f, Dv = 0.f;
        while (m) {                       // ascending w == reference order
            int w = __ffs(m) - 1;
            m &= (m - 1);
            float2 rr = srr[w];
            float2 kw = kv[w][hd];
            A  = fmaf(rr.x, kw.x, A);  Bv = fmaf(rr.y, kw.x, Bv);
            Cv = fmaf(rr.x, kw.y, Cv); Dv = fmaf(rr.y, kw.y, Dv);
        }
        Bv += srb2k[hd];
        Dv += srb2v[hd];
        float* tf = (float*)sT;
        tf[(0 * TSZ + p * TROW) * 4 + hd] = A;
        tf[(1 * TSZ + p * TROW) * 4 + hd] = Bv;
        tf[(2 * TSZ + p * TROW) * 4 + hd] = Cv;
        tf[(3 * TSZ + p * TROW) * 4 + hd] = Dv;
    }
    __syncthreads();   // B3: table ready

    // ---- logits via PWL table ----
    int p = 0;
#pragma unroll
    for (int k = 0; k < 32; k++) p += (sts[k] < dist) ? 1 : 0;

    const float4* Ap = sT + 0 * TSZ + p * TROW;
    const float4* Bp = sT + 1 * TSZ + p * TROW;
    const float4* Cp = sT + 2 * TSZ + p * TROW;
    const float4* Dp = sT + 3 * TSZ + p * TROW;
    const float4* q04 = (const float4*)q0s;

    float lg[4] = {0.f, 0.f, 0.f, 0.f};
#pragma unroll
    for (int q = 0; q < 8; q++) {
        float4 a = Ap[q], bb = Bp[q], qq = q04[q];
        int h = q >> 1;
        lg[h] = fmaf(fmaf(dist, a.x, bb.x) * qq.x, ykr[4 * q + 0], lg[h]);
        lg[h] = fmaf(fmaf(dist, a.y, bb.y) * qq.y, ykr[4 * q + 1], lg[h]);
        lg[h] = fmaf(fmaf(dist, a.z, bb.z) * qq.z, ykr[4 * q + 2], lg[h]);
        lg[h] = fmaf(fmaf(dist, a.w, bb.w) * qq.w, ykr[4 * q + 3], lg[h]);
    }
    {
        const float invs = 0.35355339059327379f; // 1/sqrt(8)
        bool ok = okacc != 0;
#pragma unroll
        for (int h = 0; h < 4; h++) lg[h] = ok ? lg[h] * invs : -1e9f;
    }

    // block softmax over j, per head. Cross-wave reduction: write per-wave
    // partials, one barrier, every thread folds the 4 partials itself
    // (same FP order as the old tid<4 stage).
    float attn[4];
#pragma unroll
    for (int h = 0; h < 4; h++) {
        float v = lg[h];
        for (int off = 32; off; off >>= 1) v = fmaxf(v, __shfl_xor(v, off, 64));
        if (lane == 0) wredm[h][wave] = v;
    }
    __syncthreads();   // B4
    float hmv[4];
#pragma unroll
    for (int h = 0; h < 4; h++)
        hmv[h] = fmaxf(fmaxf(wredm[h][0], wredm[h][1]), fmaxf(wredm[h][2], wredm[h][3]));
#pragma unroll
    for (int h = 0; h < 4; h++) lg[h] = expf(lg[h] - hmv[h]);
#pragma unroll
    for (int h = 0; h < 4; h++) {
        float v = lg[h];
        for (int off = 32; off; off >>= 1) v += __shfl_xor(v, off, 64);
        if (lane == 0) wreds[h][wave] = v;
    }
    __syncthreads();   // B5
#pragma unroll
    for (int h = 0; h < 4; h++) {
        float hsv = wreds[h][0] + wreds[h][1] + wreds[h][2] + wreds[h][3];
        attn[h] = lg[h] / hsv;
    }

    // yv[j][0..31] projected after softmax (VGPR peak)
    float yvr[32];
#pragma unroll
    for (int hd = 0; hd < 32; hd++) yvr[hd] = 0.f;
#pragma unroll
    for (int c = 0; c < CC; c++) {
        float xc = x0n[c];
#pragma unroll
        for (int hd = 0; hd < 32; hd++)
            yvr[hd] = fmaf(xc, Mv0[c * HIDD + hd], yvr[hd]);
    }

    // v-phase with Wo0 folded
    float e[5] = {0.f, 0.f, 0.f, 0.f, 0.f};
#pragma unroll
    for (int q = 0; q < 8; q++) {
        float4 c4 = Cp[q], d4 = Dp[q];
        float at = attn[q >> 1];
        float4 pv;
        pv.x = at * fmaf(dist, c4.x, d4.x) * yvr[4 * q + 0];
        pv.y = at * fmaf(dist, c4.y, d4.y) * yvr[4 * q + 1];
        pv.z = at * fmaf(dist, c4.z, d4.z) * yvr[4 * q + 2];
        pv.w = at * fmaf(dist, c4.w, d4.w) * yvr[4 * q + 3];
#pragma unroll
        for (int c = 0; c < 5; c++) {
            float4 w4 = ((const float4*)Wo0t[c])[q];
            e[c] = fmaf(pv.x, w4.x, fmaf(pv.y, w4.y, fmaf(pv.z, w4.z, fmaf(pv.w, w4.w, e[c]))));
        }
    }
    for (int off = 32; off; off >>= 1)
#pragma unroll
        for (int c = 0; c < 5; c++) e[c] += __shfl_xor(e[c], off, 64);
    if (lane == 0)
#pragma unroll
        for (int c = 0; c < 5; c++) ew[wave][c] = e[c];
    __syncthreads();   // B6: last block-wide barrier; waves 1-3 exit after

    if (wave != 0) return;

    // ---- epilogue entirely in wave 0 (in-wave LDS ordering, no barriers) ----
    if (lane < 5) {
        float d0 = ew[0][lane] + ew[1][lane] + ew[2][lane] + ew[3][lane];
        x0as[lane] = feats[node * 5 + lane] + d0;
    }
    if (lane < 5) {
        float x0a[5], n0[5];
        float mu = 0.f;
#pragma unroll
        for (int c = 0; c < 5; c++) { x0a[c] = x0as[c]; n0[c] = fabsf(x0a[c]); mu += n0[c]; }
        mu *= 0.2f;
        float var = 0.f;
#pragma unroll
        for (int c = 0; c < 5; c++) { float d = n0[c] - mu; var += d * d; }
        var *= 0.2f;
        float sd = sqrtf(var) + 1e-8f;
        float ln = (n0[lane] - mu) / sd * gnF0[lane] + bnF0[lane];
        xfs[lane] = sgnf(x0a[lane]) * gelu_tanh(ln);
    }
    if (lane < 20) {
        float s = 0.f;
#pragma unroll
        for (int c = 0; c < 5; c++) s = fmaf(xfs[c], Wf10[c * 20 + lane], s);
        h0s[lane] = gelu_tanh(s);
    }
    if (lane < 5) {
        float f0 = 0.f;
        for (int f = 0; f < 20; f++) f0 = fmaf(h0s[f], Wf20[f * 5 + lane], f0);
        xfin[node * 5 + lane] = x0as[lane] + f0;
    }
}

// ---- Kernel 2: mean-pool + 2-layer MLP head ----
__global__ __launch_bounds__(256) void head_mlp(const float* __restrict__ xfin,
                         const float* __restrict__ Wh1, const float* __restrict__ bh1,
                         const float* __restrict__ Wh2, const float* __restrict__ bh2,
                         float* __restrict__ out) {
    __shared__ float part[2][5][25];
    __shared__ float pooled[10];
    __shared__ float hdn[2][128];
    int tid = threadIdx.x;
    if (tid < 250) {
        int b = tid / 125, r = tid % 125, c = r / 25, grp = r % 25;
        float s = 0.f;
        for (int i = grp; i < NN; i += 25) s += xfin[(b * NN + i) * 5 + c];
        part[b][c][grp] = s;
    }
    __syncthreads();
    if (tid < 10) {
        int b = tid / 5, c = tid % 5;
        float s = 0.f;
        for (int g = 0; g < 25; g++) s += part[b][c][g];
        pooled[tid] = s * (1.0f / NN);
    }
    __syncthreads();
    {
        int b = tid >> 7, k = tid & 127;
        float s = bh1[k];
#pragma unroll
        for (int c = 0; c < 5; c++) s = fmaf(pooled[b * 5 + c], Wh1[c * 128 + k], s);
        hdn[b][k] = fmaxf(s, 0.f);
    }
    __syncthreads();
    if (tid < 18) {
        int b = tid / 9, o = tid % 9;
        float s = bh2[o];
        for (int k = 0; k < 128; k++) s = fmaf(hdn[b][k], Wh2[k * 9 + o], s);
        out[b * 9 + o] = s;
    }
}

extern "C" void kernel_launch(void* const* d_in, const int* in_sizes, int n_in,
                              void* d_out, int out_size, void* d_ws, size_t ws_size,
                              hipStream_t stream) {
    const float* feats = (const float*)d_in[0];
    const float* coors = (const float*)d_in[1];
    const int*   adj   = (const int*)d_in[2];
    const float* Wq    = (const float*)d_in[3];
    const float* Mk    = (const float*)d_in[4];
    const float* Mv    = (const float*)d_in[5];
    const float* R1    = (const float*)d_in[6];
    const float* rb1   = (const float*)d_in[7];
    const float* R2    = (const float*)d_in[8];
    const float* rb2   = (const float*)d_in[9];
    const float* Wo0   = (const float*)d_in[10];
    const float* gnA   = (const float*)d_in[12];
    const float* bnA   = (const float*)d_in[13];
    const float* gnF   = (const float*)d_in[14];
    const float* bnF   = (const float*)d_in[15];
    const float* Wf1   = (const float*)d_in[16];
    const float* Wf2   = (const float*)d_in[17];
    const float* Wh1   = (const float*)d_in[20];
    const float* bh1   = (const float*)d_in[21];
    const float* Wh2   = (const float*)d_in[22];
    const float* bh2   = (const float*)d_in[23];
    float* out = (float*)d_out;

    float* xfin = (float*)d_ws;   // 512*5 floats

    hipLaunchKernelGGL(fused_attn, dim3(512), dim3(256), 0, stream,
                       coors, adj, feats, Wq, Mk, Mv, gnA, bnA, R1, rb1, R2, rb2,
                       Wo0, gnF, bnF, Wf1, Wf2, xfin);
    hipLaunchKernelGGL(head_mlp, dim3(1), dim3(256), 0, stream,
                       xfin, Wh1, bh1, Wh2, bh2, out);
}